// Round 3
// baseline (511.259 us; speedup 1.0000x reference)
//
#include <hip/hip_runtime.h>
#include <stdint.h>

constexpr int kN = 16384;
constexpr int kD = 256;
constexpr int TM = 256, TN = 256;   // block tile 256x256
constexpr int KB = kD / 2;          // fp4 row = 128 bytes

using floatx16 = __attribute__((ext_vector_type(16))) float;  // 32x32 MFMA C/D
using floatx2  = __attribute__((ext_vector_type(2))) float;   // v_pk_* pair
using intx2v   = __attribute__((ext_vector_type(2))) int;
using intx4    = __attribute__((ext_vector_type(4))) int;
using intx8    = __attribute__((ext_vector_type(8))) int;     // f8f6f4 operand

// fp32*16 -> fp4 e2m1 RNE. Codes 0..7 = {0,.5,1,1.5,2,3,4,6} ARE the bit
// patterns (monotone). Thresholds are the RNE midpoints. (R12-verified.)
__device__ __forceinline__ uint32_t q4(float x) {
    float y = fabsf(x * 16.f);
    uint32_t c = (y >= 0.25f) + (y >= 0.75f) + (y >= 1.25f) + (y >= 1.75f)
               + (y >= 2.5f)  + (y >= 3.5f)  + (y >= 5.0f);
    return c | (x < 0.f ? 8u : 0u);
}

// 8 elems -> one dword per matrix per thread (nibble i = elem 8*idx+i).
// Also zeroes the loss accumulator (replaces the memset dispatch).
__global__ __launch_bounds__(256)
void cvt_fp4_kernel(const float* __restrict__ a, const float* __restrict__ b,
                    unsigned int* __restrict__ oa, unsigned int* __restrict__ ob,
                    float* __restrict__ out) {
    int idx = blockIdx.x * 256 + threadIdx.x;
    if (idx == 0) *out = 0.f;
    float4 a0 = *(const float4*)(a + (size_t)idx * 8);
    float4 a1 = *(const float4*)(a + (size_t)idx * 8 + 4);
    float4 b0 = *(const float4*)(b + (size_t)idx * 8);
    float4 b1 = *(const float4*)(b + (size_t)idx * 8 + 4);
    uint32_t pa = q4(a0.x) | (q4(a0.y) << 4) | (q4(a0.z) << 8)  | (q4(a0.w) << 12)
                | (q4(a1.x) << 16) | (q4(a1.y) << 20) | (q4(a1.z) << 24) | (q4(a1.w) << 28);
    uint32_t pb = q4(b0.x) | (q4(b0.y) << 4) | (q4(b0.z) << 8)  | (q4(b0.w) << 12)
                | (q4(b1.x) << 16) | (q4(b1.y) << 20) | (q4(b1.z) << 24) | (q4(b1.w) << 28);
    oa[idx] = pa;
    ob[idx] = pb;
}

// Concat two quads into an 8-reg MFMA tuple (coalesces to adjacent regs).
#define CAT8(lo, hi) __builtin_shufflevector((lo), (hi), 0, 1, 2, 3, 4, 5, 6, 7)
// Rotate: odd quad into the low half; high half undef (fp4 reads only v[0:3];
// HW-validated R14/R15: absmax 0.0).
#define ROT8(v)      __builtin_shufflevector((v), (v), 4, 5, 6, 7, -1, -1, -1, -1)
#define MFMA4(a, b, c) __builtin_amdgcn_mfma_scale_f32_32x32x64_f8f6f4( \
        (a), (b), (c), 4 /*cbsz fp4*/, 4 /*blgp fp4*/, 0, 127, 0, 127)

// R16: quarter-granular ping-pong pipeline. R15's lesson: ONE shared acc
// buffer serializes EPI(prev) -> MFMA(next) (WAR) and MFMA -> own EPI (RAW);
// VALU work dropped (52->38%) but dur didn't move -> stall-bound, not
// VALU-bound. Fix: TWO 32-reg acc buffers (accA/accB). Quarter i (one 32-row
// block x both j cols, full K = 8 MFMAs) writes one buffer while the OTHER
// buffer's finished quarter is epilogued, interleaved in program order
// 1 MFMA : 8 epi-VALU per slot: while the matrix pipe holds an MFMA (~35cy),
// the wave issues the 8 independent epi insts (~16cy) -> pipe never starves.
// B double-buffered (blA/blB); a tile's buffer is reloaded for tile s+2
// right after its last MFMA reader (prefetch distance ~1 full tile).
// Budget: af8 64 + acc 64 + bl 64 + z16 16 + misc ~30 = ~238 < 256 (no R14
// spill). Gate: WRITE_SIZE ~8KB, FETCH ~9.3MB.
__global__ __launch_bounds__(512, 2)
void siglip_gemm_loss_kernel(const unsigned char* __restrict__ A,   // fp4 [N][KB]
                             const unsigned char* __restrict__ B,   // fp4 [N][KB]
                             const float* __restrict__ scale_p,
                             const float* __restrict__ bias_p,
                             float* __restrict__ out) {
    __shared__ float red[8];

    const int tid  = threadIdx.x;
    const int wave = tid >> 6;     // 0..7
    const int lane = tid & 63;

    const int g    = blockIdx.x;                  // 256 persistent blocks
    const int tRow = ((g & 7) << 3) + (g >> 5);   // fixed tile-row (A-stripe L2-hot)
    const int sCol = (g >> 3) & 3;                // tile s -> col sCol + 4s

    const int wr = wave >> 2, wc = wave & 3;   // 2x4 waves
    const int m0 = wr * 128, n0 = wc * 64;     // wave tile 128x64
    const int l31 = lane & 31;
    const int h   = lane >> 5;                 // K-half: byte offset 16h

    const float sc  = *scale_p * (1.0f / 256.0f);   // undo x16 x16 prescale
    const float bs  = *bias_p;
    const float sc3 = sc * (1.44269504f * 8388608.0f);
    const float bs3 = fmaf(bs, 1.44269504f * 8388608.0f, 1064986823.0f);
    const floatx2 sc3v = (floatx2)(sc3);
    const floatx2 bs3v = (floatx2)(bs3);

    // ---- A operand: loop-invariant, resident as intx8 pairs.
    // af8[i][p] = {quad 2p, quad 2p+1}; quad q = bytes q*32 + 16h of the row.
    intx8 af8[4][2];
    #pragma unroll
    for (int i = 0; i < 4; ++i) {
        const unsigned char* pa = A + ((size_t)tRow * TM + m0 + i * 32 + l31) * KB + 16 * h;
        #pragma unroll
        for (int p = 0; p < 2; ++p) {
            const intx4 lo = *(const intx4*)(pa + (2 * p) * 32);
            const intx4 hi = *(const intx4*)(pa + (2 * p + 1) * 32);
            af8[i][p] = CAT8(lo, hi);
        }
    }

    const floatx16 z16 = (floatx16)(0.f);   // C operand of each quarter's first MFMA

    floatx16 accA[2], accB[2];      // ping-pong quarter accumulators (32 regs each)
    floatx2 sm0 = (floatx2)(0.f), sm1 = (floatx2)(0.f);
    float smd = 0.f;                // diagonal correction accumulator

    // B addressing: walking uniform base + 32-bit voffsets. loadT calls are
    // in strictly increasing tile order, so one pointer suffices.
    const unsigned char* pb = B + (size_t)sCol * TN * KB;
    const int voff0 = (n0 + l31) * KB + 16 * h;         // j = 0 rows
    const int voff1 = voff0 + 32 * KB;                  // j = 1 rows
    const size_t tStride = (size_t)4 * TN * KB;         // tile col advances by 4

    intx8 blA[2][2], blB[2][2];     // double-buffered B tiles

    auto loadT = [&](intx8 (&bl)[2][2]) {
        #pragma unroll
        for (int j = 0; j < 2; ++j) {
            const int vo = j ? voff1 : voff0;
            #pragma unroll
            for (int p = 0; p < 2; ++p) {
                const intx4 lo = *(const intx4*)(pb + vo + (2 * p) * 32);
                const intx4 hi = *(const intx4*)(pb + vo + (2 * p + 1) * 32);
                bl[j][p] = CAT8(lo, hi);
            }
        }
        pb += tStride;
    };

    // one epi slice: 4 elems of ae starting at vb (2 pk_fma + 4 cvt + 2 pk_add)
    auto epiSlice = [&](const floatx16& ae, const int vb) {
        floatx2 t0 = {ae[vb + 0], ae[vb + 1]};
        floatx2 t1 = {ae[vb + 2], ae[vb + 3]};
        t0 = __builtin_elementwise_fma(t0, sc3v, bs3v);  // v_pk_fma_f32
        t1 = __builtin_elementwise_fma(t1, sc3v, bs3v);
        const intx2v e0 = {(int)t0.x, (int)t0.y};        // v_cvt_i32_f32
        const intx2v e1 = {(int)t1.x, (int)t1.y};
        sm0 += __builtin_bit_cast(floatx2, e0);          // v_pk_add_f32
        sm1 += __builtin_bit_cast(floatx2, e1);
    };

    // diagonal correction for an epilogued quarter (wave-uniform, rare)
    auto epiDiag = [&](const floatx16 (&ae)[2], const int iE, const int tColE) {
        #pragma unroll
        for (int j = 0; j < 2; ++j) {
            const int gRow0 = tRow * TM + m0 + iE * 32;
            const int gCol0 = tColE * TN + n0 + j * 32;
            if (gRow0 == gCol0) {
                #pragma unroll
                for (int v = 0; v < 16; ++v) {
                    const int rrow = (v & 3) + 8 * (v >> 2) + 4 * h;
                    if (rrow == l31) smd += fmaf(ae[j][v], sc, bs);
                }
            }
        }
    };

    // fused quarter step: 8 MFMAs (rows iW*32.. of the wave tile, full K) into
    // aw, interleaved 1:8 with the epilogue of ae (quarter iE, tile col tColE).
    auto qstep = [&](floatx16 (&aw)[2], const floatx16 (&ae)[2],
                     const intx8 (&bq)[2][2], const int iW, const int iE,
                     const int tColE, const bool doEpi) {
        aw[0] = MFMA4(af8[iW][0], bq[0][0], z16);
        if (doEpi) epiSlice(ae[0], 0);
        aw[1] = MFMA4(af8[iW][0], bq[1][0], z16);
        if (doEpi) epiSlice(ae[0], 4);
        const intx8 a0r = ROT8(af8[iW][0]);
        aw[0] = MFMA4(a0r, ROT8(bq[0][0]), aw[0]);
        if (doEpi) epiSlice(ae[0], 8);
        aw[1] = MFMA4(a0r, ROT8(bq[1][0]), aw[1]);
        if (doEpi) epiSlice(ae[0], 12);
        aw[0] = MFMA4(af8[iW][1], bq[0][1], aw[0]);
        if (doEpi) epiSlice(ae[1], 0);
        aw[1] = MFMA4(af8[iW][1], bq[1][1], aw[1]);
        if (doEpi) epiSlice(ae[1], 4);
        const intx8 a1r = ROT8(af8[iW][1]);
        aw[0] = MFMA4(a1r, ROT8(bq[0][1]), aw[0]);
        if (doEpi) epiSlice(ae[1], 8);
        aw[1] = MFMA4(a1r, ROT8(bq[1][1]), aw[1]);
        if (doEpi) epiSlice(ae[1], 12);
        if (doEpi) epiDiag(ae, iE, tColE);
    };

    // one tile: 4 quarter steps; quarter parity picks the acc buffer, the
    // epi'd quarter is always the other buffer (previous quarter). After the
    // last reader of this tile's B buffer, reload it for tile s+2.
    auto tileQuads = [&](intx8 (&cur)[2][2], const int s, const bool firstTile,
                         const bool doLoad) {
        const int c = sCol + 4 * s;
        qstep(accA, accB, cur, 0, 3, c - 4, !firstTile);  // epi prev tile's q3
        qstep(accB, accA, cur, 1, 0, c, true);
        qstep(accA, accB, cur, 2, 1, c, true);
        qstep(accB, accA, cur, 3, 2, c, true);
        if (doLoad) loadT(cur);                           // tile s+2, same buffer
    };

    // ---- pipelined main loop: tiles 0..15 alternate blA/blB
    loadT(blA);                     // tile 0
    loadT(blB);                     // tile 1
    tileQuads(blA, 0, true,  true); // tile 0, loads tile 2
    tileQuads(blB, 1, false, true); // tile 1, loads tile 3
    for (int sp = 1; sp < 8; ++sp) {
        tileQuads(blA, 2 * sp,     false, sp < 7);  // even tile, loads +2
        tileQuads(blB, 2 * sp + 1, false, sp < 7);  // odd tile, loads +2
    }
    // drain tile 15 quarter 3 (sits in accB)
    #pragma unroll
    for (int j2 = 0; j2 < 2; ++j2)
        #pragma unroll
        for (int vb = 0; vb < 16; vb += 4) epiSlice(accB[j2], vb);
    epiDiag(accB, 3, sCol + 60);

    float sum = (sm0.x + sm1.x) + (sm0.y + sm1.y) - smd;

    // block reduce -> ONE atomicAdd per block (256 total, spread in time)
    #pragma unroll
    for (int off = 32; off > 0; off >>= 1)
        sum += __shfl_down(sum, off);
    if (lane == 0) red[wave] = sum;
    __syncthreads();
    if (tid == 0) {
        float s2 = 0.f;
        #pragma unroll
        for (int w = 0; w < 8; ++w) s2 += red[w];
        atomicAdd(out, s2 * (1.0f / (float)kN));
    }
}

extern "C" void kernel_launch(void* const* d_in, const int* in_sizes, int n_in,
                              void* d_out, int out_size, void* d_ws, size_t ws_size,
                              hipStream_t stream) {
    const float* img     = (const float*)d_in[0];
    const float* txt     = (const float*)d_in[1];
    const float* scale_p = (const float*)d_in[2];
    const float* bias_p  = (const float*)d_in[3];
    float* out = (float*)d_out;

    unsigned char* Af4 = (unsigned char*)d_ws;            // N*KB = 2 MiB
    unsigned char* Bf4 = Af4 + (size_t)kN * KB;           // 2 MiB

    cvt_fp4_kernel<<<dim3(kN * kD / 8 / 256), dim3(256), 0, stream>>>(
        img, txt, (unsigned int*)Af4, (unsigned int*)Bf4, out);
    siglip_gemm_loss_kernel<<<dim3(256), dim3(512), 0, stream>>>(
        Af4, Bf4, scale_p, bias_p, out);
}

// Round 4
// 344.012 us; speedup vs baseline: 1.4862x; 1.4862x over previous
//
#include <hip/hip_runtime.h>
#include <stdint.h>

constexpr int kN = 16384;
constexpr int kD = 256;
constexpr int TM = 256, TN = 256;   // block tile 256x256
constexpr int KB = kD / 2;          // fp4 row = 128 bytes

using floatx16 = __attribute__((ext_vector_type(16))) float;  // 32x32 MFMA C/D
using floatx2  = __attribute__((ext_vector_type(2))) float;   // v_pk_* pair
using intx2v   = __attribute__((ext_vector_type(2))) int;
using intx4    = __attribute__((ext_vector_type(4))) int;
using intx8    = __attribute__((ext_vector_type(8))) int;     // f8f6f4 operand

// fp32*16 -> fp4 e2m1 RNE. Codes 0..7 = {0,.5,1,1.5,2,3,4,6} ARE the bit
// patterns (monotone). Thresholds are the RNE midpoints. (R12-verified.)
__device__ __forceinline__ uint32_t q4(float x) {
    float y = fabsf(x * 16.f);
    uint32_t c = (y >= 0.25f) + (y >= 0.75f) + (y >= 1.25f) + (y >= 1.75f)
               + (y >= 2.5f)  + (y >= 3.5f)  + (y >= 5.0f);
    return c | (x < 0.f ? 8u : 0u);
}

// 8 elems -> one dword per matrix per thread (nibble i = elem 8*idx+i).
// Also zeroes the loss accumulator (replaces the memset dispatch).
__global__ __launch_bounds__(256)
void cvt_fp4_kernel(const float* __restrict__ a, const float* __restrict__ b,
                    unsigned int* __restrict__ oa, unsigned int* __restrict__ ob,
                    float* __restrict__ out) {
    int idx = blockIdx.x * 256 + threadIdx.x;
    if (idx == 0) *out = 0.f;
    float4 a0 = *(const float4*)(a + (size_t)idx * 8);
    float4 a1 = *(const float4*)(a + (size_t)idx * 8 + 4);
    float4 b0 = *(const float4*)(b + (size_t)idx * 8);
    float4 b1 = *(const float4*)(b + (size_t)idx * 8 + 4);
    uint32_t pa = q4(a0.x) | (q4(a0.y) << 4) | (q4(a0.z) << 8)  | (q4(a0.w) << 12)
                | (q4(a1.x) << 16) | (q4(a1.y) << 20) | (q4(a1.z) << 24) | (q4(a1.w) << 28);
    uint32_t pb = q4(b0.x) | (q4(b0.y) << 4) | (q4(b0.z) << 8)  | (q4(b0.w) << 12)
                | (q4(b1.x) << 16) | (q4(b1.y) << 20) | (q4(b1.z) << 24) | (q4(b1.w) << 28);
    oa[idx] = pa;
    ob[idx] = pb;
}

// Concat two quads into an 8-reg MFMA tuple (coalesces to adjacent regs).
#define CAT8(lo, hi) __builtin_shufflevector((lo), (hi), 0, 1, 2, 3, 4, 5, 6, 7)
// Rotate: odd quad into the low half; high half undef (fp4 reads only v[0:3];
// HW-validated R14/R15: absmax 0.0).
#define ROT8(v)      __builtin_shufflevector((v), (v), 4, 5, 6, 7, -1, -1, -1, -1)
#define MFMA4(a, b, c) __builtin_amdgcn_mfma_scale_f32_32x32x64_f8f6f4( \
        (a), (b), (c), 4 /*cbsz fp4*/, 4 /*blgp fp4*/, 0, 127, 0, 127)

// R17: EIGHTH-granular ping-pong pipeline. R16's lesson: quarter-granular
// ping-pong (2x32 acc) + B dbuf (64) + af8 (64) + z16 (16) + ROT8/load temps
// blew the 256-reg/wave cap -> 1GB scratch. Fix: slot = ONE (i,j) 32x32
// output block, full K = 4 chained MFMAs into a single floatx16; the OTHER
// 16-reg accumulator (previous slot) is epilogued interleaved 1 MFMA : 2
// slices. Epi VALU rides in the MFMA dep-stall slots (R15 proved serial
// EPI->MFMA kills); 2 waves/SIMD anti-phase fills the rest.
// Budget: af8 64 + acc 32 + bl 64 + z16 16 = 176 + ~40 temps = ~216 < 256.
// Gate: WRITE_SIZE ~8KB / FETCH ~9.3MB (no spill), then MfmaUtil.
__global__ __launch_bounds__(512, 2)
void siglip_gemm_loss_kernel(const unsigned char* __restrict__ A,   // fp4 [N][KB]
                             const unsigned char* __restrict__ B,   // fp4 [N][KB]
                             const float* __restrict__ scale_p,
                             const float* __restrict__ bias_p,
                             float* __restrict__ out) {
    __shared__ float red[8];

    const int tid  = threadIdx.x;
    const int wave = tid >> 6;     // 0..7
    const int lane = tid & 63;

    const int g    = blockIdx.x;                  // 256 persistent blocks
    const int tRow = ((g & 7) << 3) + (g >> 5);   // fixed tile-row (A-stripe L2-hot)
    const int sCol = (g >> 3) & 3;                // tile s -> col sCol + 4s

    const int wr = wave >> 2, wc = wave & 3;   // 2x4 waves
    const int m0 = wr * 128, n0 = wc * 64;     // wave tile 128x64
    const int l31 = lane & 31;
    const int h   = lane >> 5;                 // K-half: byte offset 16h

    const float sc  = *scale_p * (1.0f / 256.0f);   // undo x16 x16 prescale
    const float bs  = *bias_p;
    const float sc3 = sc * (1.44269504f * 8388608.0f);
    const float bs3 = fmaf(bs, 1.44269504f * 8388608.0f, 1064986823.0f);
    const floatx2 sc3v = (floatx2)(sc3);
    const floatx2 bs3v = (floatx2)(bs3);

    // ---- A operand: loop-invariant, resident as intx8 pairs.
    // af8[i][p] = {quad 2p, quad 2p+1}; quad q = bytes q*32 + 16h of the row.
    intx8 af8[4][2];
    #pragma unroll
    for (int i = 0; i < 4; ++i) {
        const unsigned char* pa = A + ((size_t)tRow * TM + m0 + i * 32 + l31) * KB + 16 * h;
        #pragma unroll
        for (int p = 0; p < 2; ++p) {
            const intx4 lo = *(const intx4*)(pa + (2 * p) * 32);
            const intx4 hi = *(const intx4*)(pa + (2 * p + 1) * 32);
            af8[i][p] = CAT8(lo, hi);
        }
    }

    const floatx16 z16 = (floatx16)(0.f);   // C operand of each slot's first MFMA

    floatx16 accA, accB;            // ping-pong slot accumulators (16 regs each)
    floatx2 sm0 = (floatx2)(0.f), sm1 = (floatx2)(0.f);
    float smd = 0.f;                // diagonal correction accumulator

    // B addressing: walking uniform base (SGPR) + 32-bit voffsets.
    const unsigned char* pb = B + (size_t)sCol * TN * KB;
    const int voff0 = (n0 + l31) * KB + 16 * h;         // j = 0 rows
    const int voff1 = voff0 + 32 * KB;                  // j = 1 rows
    const size_t tStride = (size_t)4 * TN * KB;         // tile col advances by 4

    intx8 blA[2][2], blB[2][2];     // double-buffered B tiles

    auto loadT = [&](intx8 (&bl)[2][2]) {
        #pragma unroll
        for (int j = 0; j < 2; ++j) {
            const int vo = j ? voff1 : voff0;
            #pragma unroll
            for (int p = 0; p < 2; ++p) {
                const intx4 lo = *(const intx4*)(pb + vo + (2 * p) * 32);
                const intx4 hi = *(const intx4*)(pb + vo + (2 * p + 1) * 32);
                bl[j][p] = CAT8(lo, hi);
            }
        }
        pb += tStride;
    };

    // one epi slice: 4 elems of ae starting at vb (2 pk_fma + 4 cvt + 2 pk_add)
    auto epiSlice = [&](const floatx16& ae, const int vb) {
        floatx2 t0 = {ae[vb + 0], ae[vb + 1]};
        floatx2 t1 = {ae[vb + 2], ae[vb + 3]};
        t0 = __builtin_elementwise_fma(t0, sc3v, bs3v);  // v_pk_fma_f32
        t1 = __builtin_elementwise_fma(t1, sc3v, bs3v);
        const intx2v e0 = {(int)t0.x, (int)t0.y};        // v_cvt_i32_f32
        const intx2v e1 = {(int)t1.x, (int)t1.y};
        sm0 += __builtin_bit_cast(floatx2, e0);          // v_pk_add_f32
        sm1 += __builtin_bit_cast(floatx2, e1);
    };

    // diagonal correction for one epilogued slot (wave-uniform, rare)
    auto epiDiag1 = [&](const floatx16& ae, const int iE, const int jE,
                        const int tColE) {
        const int gRow0 = tRow * TM + m0 + iE * 32;
        const int gCol0 = tColE * TN + n0 + jE * 32;
        if (gRow0 == gCol0) {
            #pragma unroll
            for (int v = 0; v < 16; ++v) {
                const int rrow = (v & 3) + 8 * (v >> 2) + 4 * h;
                if (rrow == l31) smd += fmaf(ae[v], sc, bs);
            }
        }
    };

    // one slot: output block (i,j), full K = 4 chained MFMAs into aw, with the
    // previous slot's epilogue (ae) interleaved into the dep-stall slots.
    auto slotStep = [&](floatx16& aw, const floatx16& ae, const intx8 (&bq)[2][2],
                        const int i, const int j, const int iE, const int jE,
                        const int tColE, const bool doEpi) {
        aw = MFMA4(af8[i][0], bq[j][0], z16);
        if (doEpi) epiSlice(ae, 0);
        aw = MFMA4(ROT8(af8[i][0]), ROT8(bq[j][0]), aw);
        if (doEpi) epiSlice(ae, 4);
        aw = MFMA4(af8[i][1], bq[j][1], aw);
        if (doEpi) epiSlice(ae, 8);
        aw = MFMA4(ROT8(af8[i][1]), ROT8(bq[j][1]), aw);
        if (doEpi) { epiSlice(ae, 12); epiDiag1(ae, iE, jE, tColE); }
    };

    // one tile: 8 slots, parity alternates accA/accB; slot k epilogues slot
    // k-1 (previous parity). Slot 0 epilogues the previous tile's slot 7.
    // After the last reader of this tile's B buffer, reload it for tile s+2.
    auto tileSlots = [&](intx8 (&cur)[2][2], const int s, const bool firstTile,
                         const bool doLoad) {
        const int c = sCol + 4 * s;
        slotStep(accA, accB, cur, 0, 0, 3, 1, c - 4, !firstTile);
        slotStep(accB, accA, cur, 0, 1, 0, 0, c, true);
        slotStep(accA, accB, cur, 1, 0, 0, 1, c, true);
        slotStep(accB, accA, cur, 1, 1, 1, 0, c, true);
        slotStep(accA, accB, cur, 2, 0, 1, 1, c, true);
        slotStep(accB, accA, cur, 2, 1, 2, 0, c, true);
        slotStep(accA, accB, cur, 3, 0, 2, 1, c, true);
        slotStep(accB, accA, cur, 3, 1, 3, 0, c, true);
        if (doLoad) loadT(cur);                           // tile s+2, same buffer
    };

    // ---- pipelined main loop: tiles 0..15 alternate blA/blB
    loadT(blA);                     // tile 0
    loadT(blB);                     // tile 1
    tileSlots(blA, 0, true,  true); // tile 0, loads tile 2
    tileSlots(blB, 1, false, true); // tile 1, loads tile 3
    for (int sp = 1; sp < 8; ++sp) {
        tileSlots(blA, 2 * sp,     false, sp < 7);  // even tile, loads +2
        tileSlots(blB, 2 * sp + 1, false, sp < 7);  // odd tile, loads +2
    }
    // drain tile 15 slot 7 (sits in accB)
    #pragma unroll
    for (int vb = 0; vb < 16; vb += 4) epiSlice(accB, vb);
    epiDiag1(accB, 3, 1, sCol + 60);

    float sum = (sm0.x + sm1.x) + (sm0.y + sm1.y) - smd;

    // block reduce -> ONE atomicAdd per block (256 total, spread in time)
    #pragma unroll
    for (int off = 32; off > 0; off >>= 1)
        sum += __shfl_down(sum, off);
    if (lane == 0) red[wave] = sum;
    __syncthreads();
    if (tid == 0) {
        float s2 = 0.f;
        #pragma unroll
        for (int w = 0; w < 8; ++w) s2 += red[w];
        atomicAdd(out, s2 * (1.0f / (float)kN));
    }
}

extern "C" void kernel_launch(void* const* d_in, const int* in_sizes, int n_in,
                              void* d_out, int out_size, void* d_ws, size_t ws_size,
                              hipStream_t stream) {
    const float* img     = (const float*)d_in[0];
    const float* txt     = (const float*)d_in[1];
    const float* scale_p = (const float*)d_in[2];
    const float* bias_p  = (const float*)d_in[3];
    float* out = (float*)d_out;

    unsigned char* Af4 = (unsigned char*)d_ws;            // N*KB = 2 MiB
    unsigned char* Bf4 = Af4 + (size_t)kN * KB;           // 2 MiB

    cvt_fp4_kernel<<<dim3(kN * kD / 8 / 256), dim3(256), 0, stream>>>(
        img, txt, (unsigned int*)Af4, (unsigned int*)Bf4, out);
    siglip_gemm_loss_kernel<<<dim3(256), dim3(512), 0, stream>>>(
        Af4, Bf4, scale_p, bias_p, out);
}

// Round 5
// 142.882 us; speedup vs baseline: 3.5782x; 2.4077x over previous
//
#include <hip/hip_runtime.h>
#include <stdint.h>

constexpr int kN = 16384;
constexpr int kD = 256;
constexpr int KB = kD / 2;          // fp4 row = 128 bytes
constexpr int BT = 128;             // block tile: 128x128
constexpr int NCG = 6;              // col-groups (128 col-tiles split mod 6)

using floatx16 = __attribute__((ext_vector_type(16))) float;  // 32x32 MFMA C/D
using floatx2  = __attribute__((ext_vector_type(2))) float;   // v_pk_* pair
using intx2v   = __attribute__((ext_vector_type(2))) int;
using intx4    = __attribute__((ext_vector_type(4))) int;
using intx8    = __attribute__((ext_vector_type(8))) int;     // f8f6f4 operand

// fp32*16 -> fp4 e2m1 RNE. Codes 0..7 = {0,.5,1,1.5,2,3,4,6} ARE the bit
// patterns (monotone). Thresholds are the RNE midpoints. (R12-verified.)
__device__ __forceinline__ uint32_t q4(float x) {
    float y = fabsf(x * 16.f);
    uint32_t c = (y >= 0.25f) + (y >= 0.75f) + (y >= 1.25f) + (y >= 1.75f)
               + (y >= 2.5f)  + (y >= 3.5f)  + (y >= 5.0f);
    return c | (x < 0.f ? 8u : 0u);
}

// 8 elems -> one dword per matrix per thread (nibble i = elem 8*idx+i).
// Also zeroes the loss accumulator (replaces the memset dispatch).
__global__ __launch_bounds__(256)
void cvt_fp4_kernel(const float* __restrict__ a, const float* __restrict__ b,
                    unsigned int* __restrict__ oa, unsigned int* __restrict__ ob,
                    float* __restrict__ out) {
    int idx = blockIdx.x * 256 + threadIdx.x;
    if (idx == 0) *out = 0.f;
    float4 a0 = *(const float4*)(a + (size_t)idx * 8);
    float4 a1 = *(const float4*)(a + (size_t)idx * 8 + 4);
    float4 b0 = *(const float4*)(b + (size_t)idx * 8);
    float4 b1 = *(const float4*)(b + (size_t)idx * 8 + 4);
    uint32_t pa = q4(a0.x) | (q4(a0.y) << 4) | (q4(a0.z) << 8)  | (q4(a0.w) << 12)
                | (q4(a1.x) << 16) | (q4(a1.y) << 20) | (q4(a1.z) << 24) | (q4(a1.w) << 28);
    uint32_t pb = q4(b0.x) | (q4(b0.y) << 4) | (q4(b0.z) << 8)  | (q4(b0.w) << 12)
                | (q4(b1.x) << 16) | (q4(b1.y) << 20) | (q4(b1.z) << 24) | (q4(b1.w) << 28);
    oa[idx] = pa;
    ob[idx] = pb;
}

// Concat two quads into an 8-reg MFMA tuple (coalesces to adjacent regs).
#define CAT8(lo, hi) __builtin_shufflevector((lo), (hi), 0, 1, 2, 3, 4, 5, 6, 7)
// Rotate: odd quad into the low half; high half undef (fp4 reads only v[0:3];
// HW-validated R14/R15: absmax 0.0).
#define ROT8(v)      __builtin_shufflevector((v), (v), 4, 5, 6, 7, -1, -1, -1, -1)
#define MFMA4(a, b, c) __builtin_amdgcn_mfma_scale_f32_32x32x64_f8f6f4( \
        (a), (b), (c), 4 /*cbsz fp4*/, 4 /*blgp fp4*/, 0, 127, 0, 127)

// R18: TLP instead of ILP. R14/R16/R17 all spilled (WRITE_SIZE 0.5-1GB):
// fine-grained epi<->MFMA interleave + multi-buffering blows the 256-reg cap
// via scheduler-extended live ranges. R15 (phase-separated, single-buffered)
// provably does NOT spill but is stall-bound: its 2 waves/SIMD come from one
// workgroup and run lockstep -> MfmaUtil == one wave's duty (~29%). Fix:
// 256-thread blocks (4 waves, 2x2 of 64x64 wave-tiles, block tile 128x128),
// __launch_bounds__(256,3) -> 3 blocks/CU -> every SIMD hosts 3 waves from
// THREE DIFFERENT blocks (different start times, different tiles) -> natural
// anti-phase; matrix pipe demand 3x566cy per ~850cy period = saturated.
// Budget: af8 32 + bl 32 + acc 32 + z16 16 + misc ~45 = ~160 <= 170 (=512/3).
// Grid: 128 row-stripes x 6 col-groups = 768 = exactly 3/CU, no tail rounds;
// col-tiles by residue mod 6 (22/22/21/21/21/21).
__global__ __launch_bounds__(256, 3)
void siglip_gemm_loss_kernel(const unsigned char* __restrict__ A,   // fp4 [N][KB]
                             const unsigned char* __restrict__ B,   // fp4 [N][KB]
                             const float* __restrict__ scale_p,
                             const float* __restrict__ bias_p,
                             float* __restrict__ out) {
    __shared__ float red[4];

    const int tid  = threadIdx.x;
    const int wave = tid >> 6;     // 0..3
    const int lane = tid & 63;

    const int g      = blockIdx.x;            // 768 blocks
    const int stripe = g / NCG;               // row-stripe 0..127
    const int cg     = g - NCG * stripe;      // col-group 0..5
    const int nT     = (133 - cg) / 6;        // 22,22,21,21,21,21 tiles

    const int wr = wave >> 1, wc = wave & 1;  // 2x2 waves
    const int m0 = wr * 64, n0 = wc * 64;     // wave tile 64x64
    const int l31 = lane & 31;
    const int h   = lane >> 5;                // K-half: byte offset 16h

    const float sc  = *scale_p * (1.0f / 256.0f);   // undo x16 x16 prescale
    const float bs  = *bias_p;
    const float sc3 = sc * (1.44269504f * 8388608.0f);
    const float bs3 = fmaf(bs, 1.44269504f * 8388608.0f, 1064986823.0f);
    const floatx2 sc3v = (floatx2)(sc3);
    const floatx2 bs3v = (floatx2)(bs3);

    // ---- A operand: loop-invariant, resident as intx8 pairs (2 row-blocks).
    // af8[i][p] = {quad 2p, quad 2p+1}; quad q = bytes q*32 + 16h of the row.
    intx8 af8[2][2];
    const int rowBase = stripe * BT + m0;
    #pragma unroll
    for (int i = 0; i < 2; ++i) {
        const unsigned char* pa = A + ((size_t)rowBase + i * 32 + l31) * KB + 16 * h;
        #pragma unroll
        for (int p = 0; p < 2; ++p) {
            const intx4 lo = *(const intx4*)(pa + (2 * p) * 32);
            const intx4 hi = *(const intx4*)(pa + (2 * p + 1) * 32);
            af8[i][p] = CAT8(lo, hi);
        }
    }

    const floatx16 z16 = (floatx16)(0.f);   // C operand of each half's first MFMA

    floatx16 acc[2];                 // ONE half (1 row-block x 2 col-blocks)
    floatx2 sm0 = (floatx2)(0.f), sm1 = (floatx2)(0.f);
    float smd = 0.f;                 // diagonal correction accumulator

    // B addressing: walking uniform base + 32-bit voffsets.
    const unsigned char* pb = B + (size_t)cg * BT * KB;
    const int voff0 = (n0 + l31) * KB + 16 * h;         // j = 0 rows
    const int voff1 = voff0 + 32 * KB;                  // j = 1 rows
    const size_t tStride = (size_t)NCG * BT * KB;       // tile col advances by 6

    intx8 bl[2][2];   // [j][p] single-buffered B tile (R15-proven)

    auto loadT = [&]() {
        #pragma unroll
        for (int j = 0; j < 2; ++j) {
            const int vo = j ? voff1 : voff0;
            #pragma unroll
            for (int p = 0; p < 2; ++p) {
                const intx4 lo = *(const intx4*)(pb + vo + (2 * p) * 32);
                const intx4 hi = *(const intx4*)(pb + vo + (2 * p + 1) * 32);
                bl[j][p] = CAT8(lo, hi);
            }
        }
        pb += tStride;
    };

    // 8 MFMAs of row-block i, full K, into acc[0..1] (consecutive MFMAs
    // alternate j -> dep chains are 4-long with 2-slot spacing).
    auto mfmaH = [&](const int i) {
        acc[0] = MFMA4(af8[i][0], bl[0][0], z16);
        acc[1] = MFMA4(af8[i][0], bl[1][0], z16);
        acc[0] = MFMA4(ROT8(af8[i][0]), ROT8(bl[0][0]), acc[0]);
        acc[1] = MFMA4(ROT8(af8[i][0]), ROT8(bl[1][0]), acc[1]);
        acc[0] = MFMA4(af8[i][1], bl[0][1], acc[0]);
        acc[1] = MFMA4(af8[i][1], bl[1][1], acc[1]);
        acc[0] = MFMA4(ROT8(af8[i][1]), ROT8(bl[0][1]), acc[0]);
        acc[1] = MFMA4(ROT8(af8[i][1]), ROT8(bl[1][1]), acc[1]);
    };

    // Schraudolph epilogue of one half (32 elems), packed 2-wide.
    auto epiH = [&](const int iE, const int c) {
        #pragma unroll
        for (int j = 0; j < 2; ++j) {
            const floatx16 a = acc[j];
            #pragma unroll
            for (int v = 0; v < 16; v += 4) {
                floatx2 t0 = {a[v + 0], a[v + 1]};
                floatx2 t1 = {a[v + 2], a[v + 3]};
                t0 = __builtin_elementwise_fma(t0, sc3v, bs3v);  // v_pk_fma_f32
                t1 = __builtin_elementwise_fma(t1, sc3v, bs3v);
                const intx2v e0 = {(int)t0.x, (int)t0.y};        // v_cvt_i32_f32
                const intx2v e1 = {(int)t1.x, (int)t1.y};
                sm0 += __builtin_bit_cast(floatx2, e0);          // v_pk_add_f32
                sm1 += __builtin_bit_cast(floatx2, e1);
            }
            // diagonal correction: term_diag = term_off - t
            const int gRow0 = rowBase + iE * 32;
            const int gCol0 = c * BT + n0 + j * 32;
            if (gRow0 == gCol0) {   // wave-uniform, rare
                #pragma unroll
                for (int v = 0; v < 16; ++v) {
                    const int rrow = (v & 3) + 8 * (v >> 2) + 4 * h;
                    if (rrow == l31) smd += fmaf(a[v], sc, bs);
                }
            }
        }
    };

    // ---- phase-separated main loop (R15 shape, halved wave-tile).
    // Col-tile index of step s is cg + 6s. Cross-wave TLP (3 blocks/CU,
    // desynced) hides the per-wave E->M serialization; no in-wave tricks.
    loadT();                        // tile 0
    mfmaH(0);                       // M h0(0)
    epiH(0, cg);                    // E h0(0)
    mfmaH(1);                       // M h1(0)
    for (int s = 1; s < nT; ++s) {
        const int cPrev = cg + 6 * (s - 1);
        loadT();                    // tile s (gap to first use = E h1)
        epiH(1, cPrev);             // E h1(s-1)
        mfmaH(0);                   // M h0(s)
        epiH(0, cPrev + 6);         // E h0(s)
        mfmaH(1);                   // M h1(s)
    }
    epiH(1, cg + 6 * (nT - 1));     // drain last tile's h1

    float sum = (sm0.x + sm1.x) + (sm0.y + sm1.y) - smd;

    // block reduce -> ONE atomicAdd per block (768 total, spread in time)
    #pragma unroll
    for (int off = 32; off > 0; off >>= 1)
        sum += __shfl_down(sum, off);
    if (lane == 0) red[wave] = sum;
    __syncthreads();
    if (tid == 0) {
        float s2 = 0.f;
        #pragma unroll
        for (int w = 0; w < 4; ++w) s2 += red[w];
        atomicAdd(out, s2 * (1.0f / (float)kN));
    }
}

extern "C" void kernel_launch(void* const* d_in, const int* in_sizes, int n_in,
                              void* d_out, int out_size, void* d_ws, size_t ws_size,
                              hipStream_t stream) {
    const float* img     = (const float*)d_in[0];
    const float* txt     = (const float*)d_in[1];
    const float* scale_p = (const float*)d_in[2];
    const float* bias_p  = (const float*)d_in[3];
    float* out = (float*)d_out;

    unsigned char* Af4 = (unsigned char*)d_ws;            // N*KB = 2 MiB
    unsigned char* Bf4 = Af4 + (size_t)kN * KB;           // 2 MiB

    cvt_fp4_kernel<<<dim3(kN * kD / 8 / 256), dim3(256), 0, stream>>>(
        img, txt, (unsigned int*)Af4, (unsigned int*)Bf4, out);
    siglip_gemm_loss_kernel<<<dim3(128 * NCG), dim3(256), 0, stream>>>(
        Af4, Bf4, scale_p, bias_p, out);
}